// Round 1
// baseline (892.408 us; speedup 1.0000x reference)
//
#include <hip/hip_runtime.h>

// Delta-modulation encoder: x (B,C,T) f32 -> spikes {-1,0,1} f32.
// Strictly sequential recurrence per (b,c) channel; must be bit-exact vs
// numpy f32 reference. One thread per channel (2048 threads), 4-deep
// chunk prefetch pipeline to hide HBM latency at 1 wave/SIMD occupancy.

constexpr int T_LEN = 16384;
constexpr int CH    = 32;   // floats per chunk (8 x float4)

struct Chunk { float4 v0, v1, v2, v3, v4, v5, v6, v7; };

__device__ __forceinline__ Chunk load_chunk(const float* __restrict__ p) {
    const float4* q = reinterpret_cast<const float4*>(p);
    Chunk c;
    c.v0 = q[0]; c.v1 = q[1]; c.v2 = q[2]; c.v3 = q[3];
    c.v4 = q[4]; c.v5 = q[5]; c.v6 = q[6]; c.v7 = q[7];
    return c;
}

// One recurrence step. Exact f32 semantics of the reference:
//   err = fl(x - r); pos = err > th; neg = err < -th;
//   r'  = fl(r + net*th)  with net*th in {+th, 0, -th} exact.
// d = fl(r+th), e = fl(r-th) are computed off the critical chain; the chain
// is sub -> cmp -> cndmask -> cndmask (4 dependent VALU ops).
#define DM_STEP(X, O)                                   \
    {                                                   \
        float d   = r + th;                             \
        float e   = r - th;                             \
        float err = (X) - r;                            \
        bool  p   = err > th;                           \
        bool  n   = err < -th;                          \
        (O)       = p ? 1.0f : (n ? -1.0f : 0.0f);      \
        float rn  = p ? d : r;                          \
        r         = n ? e : rn;                         \
    }

__device__ __forceinline__ float4 step4(const float4 xv, float& r, const float th) {
    float4 o;
    DM_STEP(xv.x, o.x)
    DM_STEP(xv.y, o.y)
    DM_STEP(xv.z, o.z)
    DM_STEP(xv.w, o.w)
    return o;
}

__device__ __forceinline__ void proc_chunk(const Chunk& c, float* __restrict__ outp,
                                           float& r, const float th) {
    float4* q = reinterpret_cast<float4*>(outp);
    q[0] = step4(c.v0, r, th);
    q[1] = step4(c.v1, r, th);
    q[2] = step4(c.v2, r, th);
    q[3] = step4(c.v3, r, th);
    q[4] = step4(c.v4, r, th);
    q[5] = step4(c.v5, r, th);
    q[6] = step4(c.v6, r, th);
    q[7] = step4(c.v7, r, th);
}

__global__ void dm_encode_kernel(const float* __restrict__ x,
                                 const float* __restrict__ thp,
                                 float* __restrict__ out,
                                 const int nseq) {
    const int s = blockIdx.x * blockDim.x + threadIdx.x;
    if (s >= nseq) return;

    // clip(threshold, 0.01, 0.5) — threshold is a device-side scalar input
    const float th = fminf(fmaxf(thp[0], 0.01f), 0.5f);

    const float* __restrict__ xs = x   + (size_t)s * T_LEN;
    float* __restrict__       os = out + (size_t)s * T_LEN;

    float r = 0.0f;

    // 4-chunk rotating prefetch pipeline: loads are issued ~3 chunks
    // (~96 steps ≈ 1500 cy) before use, covering HBM miss latency with
    // only one wave per SIMD.
    Chunk c0 = load_chunk(xs + 0 * CH);
    Chunk c1 = load_chunk(xs + 1 * CH);
    Chunk c2 = load_chunk(xs + 2 * CH);

    for (int t = 0; t < T_LEN; t += 4 * CH) {
        Chunk c3 = load_chunk(xs + t + 3 * CH);   // always in-bounds: t <= T-128

        proc_chunk(c0, os + t + 0 * CH, r, th);
        if (t + 4 * CH < T_LEN) c0 = load_chunk(xs + t + 4 * CH);

        proc_chunk(c1, os + t + 1 * CH, r, th);
        if (t + 5 * CH < T_LEN) c1 = load_chunk(xs + t + 5 * CH);

        proc_chunk(c2, os + t + 2 * CH, r, th);
        if (t + 6 * CH < T_LEN) c2 = load_chunk(xs + t + 6 * CH);

        proc_chunk(c3, os + t + 3 * CH, r, th);
    }
}

extern "C" void kernel_launch(void* const* d_in, const int* in_sizes, int n_in,
                              void* d_out, int out_size, void* d_ws, size_t ws_size,
                              hipStream_t stream) {
    const float* x   = (const float*)d_in[0];
    const float* thp = (const float*)d_in[1];
    float* out       = (float*)d_out;

    const int nseq = in_sizes[0] / T_LEN;   // B*C = 2048
    const int block = 64;
    const int grid  = (nseq + block - 1) / block;

    dm_encode_kernel<<<grid, block, 0, stream>>>(x, thp, out, nseq);
}

// Round 3
// 668.167 us; speedup vs baseline: 1.3356x; 1.3356x over previous
//
#include <hip/hip_runtime.h>

// Delta-modulation encoder: x (B,C,T) f32 -> spikes {-1,0,1} f32.
// Strictly sequential recurrence per (b,c) channel; must be bit-exact vs
// numpy f32 reference. One thread per channel (2048 threads = 32 waves),
// so inherently 1 wave/SIMD: latency hiding must come from in-register
// prefetch, NOT TLP. __launch_bounds__(64,1) legalizes ~512 VGPRs so the
// 4-deep chunk pipeline survives register allocation (round-1 failure:
// compiler capped at 64 VGPRs and collapsed the pipeline -> 107 cy/step).

constexpr int T_LEN = 16384;
constexpr int CH    = 32;   // floats per chunk (8 x float4)

struct Chunk { float4 v0, v1, v2, v3, v4, v5, v6, v7; };

__device__ __forceinline__ Chunk load_chunk(const float* __restrict__ p) {
    const float4* q = reinterpret_cast<const float4*>(p);
    Chunk c;
    c.v0 = q[0]; c.v1 = q[1]; c.v2 = q[2]; c.v3 = q[3];
    c.v4 = q[4]; c.v5 = q[5]; c.v6 = q[6]; c.v7 = q[7];
    return c;
}

// One recurrence step. Exact f32 semantics of the reference:
//   err = fl(x - r); pos = err > th; neg = err < -th;
//   r'  = fl(r + net*th)  with net*th in {+th, 0, -th} exact.
// d = fl(r+th), e = fl(r-th) are off the critical chain; the chain is
// sub -> cmp -> cndmask -> cndmask (4 dependent VALU ops).
#define DM_STEP(X, O)                                   \
    {                                                   \
        float d   = r + th;                             \
        float e   = r - th;                             \
        float err = (X) - r;                            \
        bool  p   = err > th;                           \
        bool  n   = err < -th;                          \
        (O)       = p ? 1.0f : (n ? -1.0f : 0.0f);      \
        float rn  = p ? d : r;                          \
        r         = n ? e : rn;                         \
    }

__device__ __forceinline__ float4 step4(const float4 xv, float& r, const float th) {
    float4 o;
    DM_STEP(xv.x, o.x)
    DM_STEP(xv.y, o.y)
    DM_STEP(xv.z, o.z)
    DM_STEP(xv.w, o.w)
    return o;
}

__device__ __forceinline__ void proc_chunk(const Chunk& c, float* __restrict__ outp,
                                           float& r, const float th) {
    float4* q = reinterpret_cast<float4*>(outp);
    q[0] = step4(c.v0, r, th);
    q[1] = step4(c.v1, r, th);
    q[2] = step4(c.v2, r, th);
    q[3] = step4(c.v3, r, th);
    q[4] = step4(c.v4, r, th);
    q[5] = step4(c.v5, r, th);
    q[6] = step4(c.v6, r, th);
    q[7] = step4(c.v7, r, th);
}

__global__ void __launch_bounds__(64, 1)
dm_encode_kernel(const float* __restrict__ x,
                 const float* __restrict__ thp,
                 float* __restrict__ out,
                 const int nseq) {
    const int s = blockIdx.x * blockDim.x + threadIdx.x;
    if (s >= nseq) return;

    // clip(threshold, 0.01, 0.5) — threshold is a device-side scalar input
    const float th = fminf(fmaxf(thp[0], 0.01f), 0.5f);

    const float* __restrict__ xs = x   + (size_t)s * T_LEN;
    float* __restrict__       os = out + (size_t)s * T_LEN;

    float r = 0.0f;

    // 4-chunk rotating prefetch pipeline: loads are issued ~3 chunks
    // (~96 steps, ~1900 cy of chain work) before use, covering the ~900 cy
    // HBM miss latency with only one wave per SIMD.
    Chunk c0 = load_chunk(xs + 0 * CH);
    Chunk c1 = load_chunk(xs + 1 * CH);
    Chunk c2 = load_chunk(xs + 2 * CH);

    for (int t = 0; t < T_LEN; t += 4 * CH) {
        Chunk c3 = load_chunk(xs + t + 3 * CH);   // always in-bounds: t <= T-128

        proc_chunk(c0, os + t + 0 * CH, r, th);
        if (t + 4 * CH < T_LEN) c0 = load_chunk(xs + t + 4 * CH);

        proc_chunk(c1, os + t + 1 * CH, r, th);
        if (t + 5 * CH < T_LEN) c1 = load_chunk(xs + t + 5 * CH);

        proc_chunk(c2, os + t + 2 * CH, r, th);
        if (t + 6 * CH < T_LEN) c2 = load_chunk(xs + t + 6 * CH);

        proc_chunk(c3, os + t + 3 * CH, r, th);
    }
}

extern "C" void kernel_launch(void* const* d_in, const int* in_sizes, int n_in,
                              void* d_out, int out_size, void* d_ws, size_t ws_size,
                              hipStream_t stream) {
    const float* x   = (const float*)d_in[0];
    const float* thp = (const float*)d_in[1];
    float* out       = (float*)d_out;

    const int nseq = in_sizes[0] / T_LEN;   // B*C = 2048
    const int block = 64;
    const int grid  = (nseq + block - 1) / block;

    dm_encode_kernel<<<grid, block, 0, stream>>>(x, thp, out, nseq);
}

// Round 4
// 640.792 us; speedup vs baseline: 1.3927x; 1.0427x over previous
//
#include <hip/hip_runtime.h>
#include <stdint.h>

// Delta-modulation encoder: x (B,C,T) f32 -> spikes {-1,0,1} f32.
// Bit-exact f32 recurrence per channel (trajectory must match numpy exactly;
// the spike VALUES only need 2e-2 abs tolerance).
//
// Round-3 lesson: 2048 channels as 32 waves = 32 CUs -> per-CU load-issue
// caps HBM at ~768 GB/s (measured 396 GB/s), a >330us memory floor.
// Restructure: 256 blocks x 1 wave, K=8 channels per wave (8 compute lanes).
//  - all 64 lanes stage input windows via global_load_lds (async DMA,
//    coalesced ~128B/channel-group per instr), double-buffered in LDS
//  - XOR-granule LDS layout (granule = k*64 + c*8 + (q^c)), achieved by
//    permuting the per-lane GLOBAL src (DMA LDS dest must stay linear);
//    the 8 compute lanes' ds_read_b128 then hit 8 disjoint bank quads
//  - single-wave blocks: no barriers, just counted s_waitcnt vmcnt(0)
//    once per window (stall amortized over 512 steps)
//  - chains are latency-bound (4 dependent VALU/step); 8 chains share each
//    wave's instruction issue.

constexpr int T_LEN = 16384;
constexpr int W     = 512;           // floats per channel per window
constexpr int NWIN  = T_LEN / W;     // 32
constexpr int K     = 8;             // channels per block (one wave)

typedef __attribute__((address_space(3))) uint32_t lds_u32;
typedef __attribute__((address_space(1))) uint32_t glb_u32;

__device__ __forceinline__ void gld_lds16(const float* gsrc, float4* ldst) {
    __builtin_amdgcn_global_load_lds((const glb_u32*)gsrc, (lds_u32*)ldst, 16, 0, 0);
}

// One recurrence step, exact f32 semantics of the reference.
// Chain: sub -> cmp -> cndmask -> cndmask. d,e off-chain.
#define DM_STEP(X, O)                                   \
    {                                                   \
        float d   = r + th;                             \
        float e   = r + nth;                            \
        float err = (X) - r;                            \
        bool  p   = err > th;                           \
        bool  n   = err < nth;                          \
        (O)       = p ? 1.0f : (n ? -1.0f : 0.0f);      \
        float rn  = p ? d : r;                          \
        r         = n ? e : rn;                         \
    }

__device__ __forceinline__ float4 step4(const float4 xv, float& r,
                                        const float th, const float nth) {
    float4 o;
    DM_STEP(xv.x, o.x)
    DM_STEP(xv.y, o.y)
    DM_STEP(xv.z, o.z)
    DM_STEP(xv.w, o.w)
    return o;
}

// Stage one window (W floats for each of K channels) into LDS half `half`.
// Lane l: c = l>>3 (channel in group), m4 = (l&7)^c (granule permute).
// DMA dest is linear (base + lane*16); the granule permutation is applied
// on the SOURCE address so that reads can use the conflict-free mapping.
__device__ __forceinline__ void stage_window(const float* __restrict__ x,
                                             int seq_base, int nseq, int win,
                                             float4* lds_half, int lane) {
    const int c  = lane >> 3;
    const int m4 = (lane & 7) ^ c;
    int seq = seq_base + c;
    if (seq >= nseq) seq = nseq - 1;             // clamp: duplicate, unused
    const float* src0 = x + (size_t)seq * T_LEN + (size_t)win * W + m4 * 4;
    #pragma unroll
    for (int k = 0; k < W / 32; ++k) {           // 16 DMA instrs / window
        gld_lds16(src0 + k * 32, lds_half + k * 64);
    }
}

__global__ void __launch_bounds__(64, 1)
dm_encode_kernel(const float* __restrict__ x,
                 const float* __restrict__ thp,
                 float* __restrict__ out,
                 const int nseq) {
    // 2 halves x K*W floats = 2 x 16KB = 32 KiB, as float4 granules
    __shared__ float4 xb4[2 * K * W / 4];

    const int lane     = threadIdx.x;
    const int seq_base = blockIdx.x * K;

    const float th  = fminf(fmaxf(thp[0], 0.01f), 0.5f);
    const float nth = -th;

    // stage window 0 into half 0 (all 64 lanes)
    stage_window(x, seq_base, nseq, 0, xb4, lane);

    const int  c    = lane;                       // compute lane = channel
    const bool comp = (lane < K) && (seq_base + lane < nseq);
    float r = 0.0f;

    float4* po = nullptr;
    if (comp) po = reinterpret_cast<float4*>(out + (size_t)(seq_base + c) * T_LEN);

    for (int win = 0; win < NWIN; ++win) {
        const int half = win & 1;

        // stage(win) done; prior window's stores drained (amortized ~3%)
        asm volatile("s_waitcnt vmcnt(0)" ::: "memory");

        // prefetch next window into the other half (async, all lanes)
        if (win + 1 < NWIN)
            stage_window(x, seq_base, nseq, win + 1, xb4 + (half ^ 1) * (K * W / 4), lane);

        if (comp) {
            const float4* lb = xb4 + half * (K * W / 4);
            const int cg = c * 8;
            // j = k*8 + q ; granule = k*64 + c*8 + (q^c)   (conflict-free)
            float4 a = lb[cg + (0 ^ c)];
            float4 b = lb[cg + (1 ^ c)];
            #pragma unroll 8
            for (int j = 0; j < W / 4; ++j) {
                const int jj = (j + 2) & (W / 4 - 1);      // wrap: harmless re-read
                float4 nxt = lb[((jj >> 3) << 6) + cg + ((jj & 7) ^ c)];
                float4 o = step4(a, r, th, nth);
                po[win * (W / 4) + j] = o;                 // 16B store, own channel
                a = b; b = nxt;
            }
        }
    }
}

extern "C" void kernel_launch(void* const* d_in, const int* in_sizes, int n_in,
                              void* d_out, int out_size, void* d_ws, size_t ws_size,
                              hipStream_t stream) {
    const float* x   = (const float*)d_in[0];
    const float* thp = (const float*)d_in[1];
    float* out       = (float*)d_out;

    const int nseq = in_sizes[0] / T_LEN;           // B*C = 2048
    const int grid = (nseq + K - 1) / K;            // 256 blocks, 1 wave each

    dm_encode_kernel<<<grid, 64, 0, stream>>>(x, thp, out, nseq);
}

// Round 5
// 529.390 us; speedup vs baseline: 1.6857x; 1.2104x over previous
//
#include <hip/hip_runtime.h>
#include <stdint.h>

// Delta-modulation encoder: x (B,C,T) f32 -> spikes {-1,0,1} f32.
// Bit-exact f32 recurrence per channel. 256 blocks x 1 wave x 8 channels
// (lanes 0-7 compute; all 64 lanes stage via global_load_lds DMA).
// Wall time == single-wave cy/step (no TLP exists: 2048 chains only).
// Round-4: 71 cy/step, VALUBusy 52% on busy SIMD -> stalls + fat step.
// This round: 7-VALU step (abs-compare + copysign, one shared vcc),
// 32-step register burst groups (8x ds_read_b128, A/B double buffer,
// consumed a full group later -> LDS latency hidden). Floor ~16 cy/step.

constexpr int T_LEN  = 16384;
constexpr int W      = 512;           // floats per channel per window
constexpr int NWIN   = T_LEN / W;     // 32
constexpr int K      = 8;             // channels per block (one wave)
constexpr int HALF_G = K * W / 4;     // 1024 float4 granules per LDS half

typedef __attribute__((address_space(3))) uint32_t lds_u32;
typedef __attribute__((address_space(1))) uint32_t glb_u32;

__device__ __forceinline__ void gld_lds16(const float* gsrc, float4* ldst) {
    __builtin_amdgcn_global_load_lds((const glb_u32*)gsrc, (lds_u32*)ldst, 16, 0, 0);
}

// Stage one window (W floats x K channels) into an LDS half via DMA.
// LDS granule layout: granule(c, j) = (j>>3)*64 + c*8 + ((j&7)^c)
// (j = float4 index within the channel's window). DMA dest is linear
// (uniform base + lane*16); the XOR permute is applied on the per-lane
// GLOBAL source address (both-sides-or-neither, rule 21). Verified
// bit-exact in rounds 3-4.
__device__ __forceinline__ void stage_window(const float* __restrict__ x,
                                             int seq_base, int nseq, int win,
                                             float4* lds_half, int lane) {
    const int c  = lane >> 3;
    const int m4 = (lane & 7) ^ c;
    int seq = seq_base + c;
    if (seq >= nseq) seq = nseq - 1;             // clamp: duplicate, unused
    const float* src0 = x + (size_t)seq * T_LEN + (size_t)win * W + m4 * 4;
    #pragma unroll
    for (int k = 0; k < W / 32; ++k) {           // 16 DMA instrs / window
        gld_lds16(src0 + k * 32, lds_half + k * 64);
    }
}

// One step, exact f32 semantics of the reference:
//   err = fl(x-r); m = |err|>th; spike = m ? copysign(1,err) : 0;
//   r'  = m ? fl(r + copysign(th,err)) : r.
// 7 VALU: sub, cmp(abs mod), bfi, add, cndmask, bfi, cndmask (shared vcc).
__device__ __forceinline__ float dm_step(const float xv, float& r, const float th) {
    const float err = xv - r;
    const bool  m   = fabsf(err) > th;
    const float rc  = r + copysignf(th, err);
    const float o   = m ? copysignf(1.0f, err) : 0.0f;
    r = m ? rc : r;
    return o;
}

__device__ __forceinline__ float4 step4(const float4 xv, float& r, const float th) {
    float4 o;
    o.x = dm_step(xv.x, r, th);
    o.y = dm_step(xv.y, r, th);
    o.z = dm_step(xv.z, r, th);
    o.w = dm_step(xv.w, r, th);
    return o;
}

// Load group g (8 float4s = 32 steps) for this lane's channel.
// lb already includes c*8; index = g*64 + (q^c)  -> conflict-free
// (bank-quad = q^c, distinct across the 8 compute lanes).
#define LOADG(d, g)                                                     \
    d##0 = lb[(g) * 64 + (0 ^ c)]; d##1 = lb[(g) * 64 + (1 ^ c)];       \
    d##2 = lb[(g) * 64 + (2 ^ c)]; d##3 = lb[(g) * 64 + (3 ^ c)];       \
    d##4 = lb[(g) * 64 + (4 ^ c)]; d##5 = lb[(g) * 64 + (5 ^ c)];       \
    d##6 = lb[(g) * 64 + (6 ^ c)]; d##7 = lb[(g) * 64 + (7 ^ c)];

// Compute + store group g from registers (q ascending = time order).
#define COMPG(s, g)                                                     \
    pw[(g) * 8 + 0] = step4(s##0, r, th);                               \
    pw[(g) * 8 + 1] = step4(s##1, r, th);                               \
    pw[(g) * 8 + 2] = step4(s##2, r, th);                               \
    pw[(g) * 8 + 3] = step4(s##3, r, th);                               \
    pw[(g) * 8 + 4] = step4(s##4, r, th);                               \
    pw[(g) * 8 + 5] = step4(s##5, r, th);                               \
    pw[(g) * 8 + 6] = step4(s##6, r, th);                               \
    pw[(g) * 8 + 7] = step4(s##7, r, th);

__global__ void __launch_bounds__(64, 1)
dm_encode_kernel(const float* __restrict__ x,
                 const float* __restrict__ thp,
                 float* __restrict__ out,
                 const int nseq) {
    __shared__ float4 xb4[2 * HALF_G];            // 32 KiB, double-buffered

    const int lane     = threadIdx.x;
    const int seq_base = blockIdx.x * K;
    const float th     = fminf(fmaxf(thp[0], 0.01f), 0.5f);

    stage_window(x, seq_base, nseq, 0, xb4, lane);

    const int  c    = lane;
    const bool comp = (lane < K) && (seq_base + lane < nseq);
    float r = 0.0f;
    float4* po = nullptr;
    if (comp) po = reinterpret_cast<float4*>(out + (size_t)(seq_base + c) * T_LEN);

    for (int win = 0; win < NWIN; ++win) {
        const int half = win & 1;

        // stage(win) complete; prior window's stores drained (~0.6 cy/step)
        asm volatile("s_waitcnt vmcnt(0)" ::: "memory");

        if (win + 1 < NWIN)
            stage_window(x, seq_base, nseq, win + 1,
                         xb4 + (half ^ 1) * HALF_G, lane);

        if (comp) {
            const float4* lb = xb4 + half * HALF_G + c * 8;
            float4* pw = po + win * (W / 4);

            float4 a0, a1, a2, a3, a4, a5, a6, a7;
            float4 b0, b1, b2, b3, b4, b5, b6, b7;
            LOADG(a, 0)                            // group 0 preload

            #pragma unroll 1
            for (int i = 0; i < 7; ++i) {          // groups 2i, 2i+1
                const int gA = 2 * i;
                LOADG(b, gA + 1)                   // B in flight over COMPG(a)
                COMPG(a, gA)
                LOADG(a, gA + 2)                   // next A over COMPG(b)
                COMPG(b, gA + 1)
            }
            LOADG(b, 15)
            COMPG(a, 14)
            COMPG(b, 15)
        }
    }
}

extern "C" void kernel_launch(void* const* d_in, const int* in_sizes, int n_in,
                              void* d_out, int out_size, void* d_ws, size_t ws_size,
                              hipStream_t stream) {
    const float* x   = (const float*)d_in[0];
    const float* thp = (const float*)d_in[1];
    float* out       = (float*)d_out;

    const int nseq = in_sizes[0] / T_LEN;           // B*C = 2048
    const int grid = (nseq + K - 1) / K;            // 256 blocks, 1 wave each

    dm_encode_kernel<<<grid, 64, 0, stream>>>(x, thp, out, nseq);
}

// Round 7
// 474.352 us; speedup vs baseline: 1.8813x; 1.1160x over previous
//
#include <hip/hip_runtime.h>
#include <stdint.h>

// Delta-modulation encoder: x (B,C,T) f32 -> spikes {-1,0,1} f32.
// Bit-exact f32 recurrence per channel. 256 blocks x 1 wave x 8 channels
// (lanes 0-7 compute; all 64 lanes stage via global_load_lds DMA).
// Per-chain rate is bounded by the 4-op dependent chain (sub->bfi->add->
// cndmask); everything else must issue in its shadow.
// Round-6 changes: 6-VALU step (o = d * fl(1/th), runtime-verified exact,
// safe 7-VALU fallback), distance-2 register group pipeline (4 rotating
// groups -> counted lgkm waits are free), counted vmcnt(48) window wait
// (DMA ops are older than the 128 stores issued after them; vmcnt retires
// in issue order -> no store-tail drain).

constexpr int T_LEN  = 16384;
constexpr int W      = 512;           // floats per channel per window
constexpr int NWIN   = T_LEN / W;     // 32
constexpr int K      = 8;             // channels per block (one wave)
constexpr int HALF_G = K * W / 4;     // 1024 float4 granules per LDS half

typedef __attribute__((address_space(3))) uint32_t lds_u32;
typedef __attribute__((address_space(1))) uint32_t glb_u32;

__device__ __forceinline__ void gld_lds16(const float* gsrc, float4* ldst) {
    __builtin_amdgcn_global_load_lds((const glb_u32*)gsrc, (lds_u32*)ldst, 16, 0, 0);
}

// Stage one window (W floats x K channels) into an LDS half via DMA.
// LDS granule layout: granule(c, j) = (j>>3)*64 + c*8 + ((j&7)^c).
// DMA dest is linear (uniform base + lane*16); the XOR permute is applied
// on the per-lane GLOBAL source address (both-sides-or-neither, rule 21).
// Verified bit-exact in rounds 3-5; conflict-free reads (PMC = 0).
__device__ __forceinline__ void stage_window(const float* __restrict__ x,
                                             int seq_base, int nseq, int win,
                                             float4* lds_half, int lane) {
    const int cc = lane >> 3;
    const int m4 = (lane & 7) ^ cc;
    int seq = seq_base + cc;
    if (seq >= nseq) seq = nseq - 1;             // clamp: duplicate, unused
    const float* src0 = x + (size_t)seq * T_LEN + (size_t)win * W + m4 * 4;
    #pragma unroll
    for (int k = 0; k < W / 32; ++k)             // 16 DMA instrs / window
        gld_lds16(src0 + k * 32, lds_half + k * 64);
}

// One step, exact f32 semantics of the reference:
//   err = fl(x-r); m = |err|>th; d = m ? copysign(th,err) : +0;
//   r' = fl(r+d)  (r+0.0f == r bitwise; r is never -0);
//   spike = m ? +-1 : 0.
// FAST: spike = d * fl(1/th) -- exact iff fl(th*fl(1/th)) == 1.0f,
// checked wave-uniformly at runtime (true for th = 0.1f).
// 6 VALU: sub, cmp(|.|), bfi, cndmask, add, mul.  Chain: sub->bfi->cndmask->add.
template<bool FAST>
__device__ __forceinline__ float dm_step(const float xv, float& r,
                                         const float th, const float inv) {
    const float err = xv - r;
    const float s   = __builtin_copysignf(th, err);
    const bool  m   = __builtin_fabsf(err) > th;
    const float d   = m ? s : 0.0f;
    r += d;
    if (FAST) return d * inv;
    const float t = __builtin_copysignf(1.0f, err);
    return m ? t : 0.0f;
}

template<bool FAST>
__device__ __forceinline__ float4 step4(const float4 xv, float& r,
                                        const float th, const float inv) {
    float4 o;
    o.x = dm_step<FAST>(xv.x, r, th, inv);
    o.y = dm_step<FAST>(xv.y, r, th, inv);
    o.z = dm_step<FAST>(xv.z, r, th, inv);
    o.w = dm_step<FAST>(xv.w, r, th, inv);
    return o;
}

// Load group g (8 float4s = 32 steps): lb includes c*8; index g*64 + (q^c)
// -> all offsets fold to ds_read_b128 immediates off one base VGPR.
#define LOADG(P, g)                                                       \
    P##0 = lb[(g) * 64 + (0 ^ c)]; P##1 = lb[(g) * 64 + (1 ^ c)];         \
    P##2 = lb[(g) * 64 + (2 ^ c)]; P##3 = lb[(g) * 64 + (3 ^ c)];         \
    P##4 = lb[(g) * 64 + (4 ^ c)]; P##5 = lb[(g) * 64 + (5 ^ c)];         \
    P##6 = lb[(g) * 64 + (6 ^ c)]; P##7 = lb[(g) * 64 + (7 ^ c)];

// Compute + store group g (q ascending = time order).
#define COMPG(P, g)                                                       \
    pw[(g) * 8 + 0] = step4<FAST>(P##0, r, th, inv);                      \
    pw[(g) * 8 + 1] = step4<FAST>(P##1, r, th, inv);                      \
    pw[(g) * 8 + 2] = step4<FAST>(P##2, r, th, inv);                      \
    pw[(g) * 8 + 3] = step4<FAST>(P##3, r, th, inv);                      \
    pw[(g) * 8 + 4] = step4<FAST>(P##4, r, th, inv);                      \
    pw[(g) * 8 + 5] = step4<FAST>(P##5, r, th, inv);                      \
    pw[(g) * 8 + 6] = step4<FAST>(P##6, r, th, inv);                      \
    pw[(g) * 8 + 7] = step4<FAST>(P##7, r, th, inv);

template<bool FAST>
__device__ __forceinline__ void run(float4* __restrict__ xb4,
                                    const float* __restrict__ x,
                                    float* __restrict__ out,
                                    const float th, const float inv,
                                    const int seq_base, const int nseq,
                                    const int lane) {
    stage_window(x, seq_base, nseq, 0, xb4, lane);

    const int  c    = lane;
    const bool comp = (lane < K) && (seq_base + lane < nseq);
    float r = 0.0f;
    float4* po = nullptr;
    if (comp) po = reinterpret_cast<float4*>(out + (size_t)(seq_base + c) * T_LEN);

    for (int win = 0; win < NWIN; ++win) {
        const int half = win & 1;

        // Guarantee DMA(win) landed. win==0: only the 16 DMA outstanding.
        // win>0: DMA(win) is older than the >=128 stores of win-1; vmcnt
        // retires in issue order, so <=48 outstanding => DMA done, without
        // draining the just-issued store tail.
        if (win == 0) asm volatile("s_waitcnt vmcnt(0)" ::: "memory");
        else          asm volatile("s_waitcnt vmcnt(48)" ::: "memory");

        if (win + 1 < NWIN)
            stage_window(x, seq_base, nseq, win + 1,
                         xb4 + (half ^ 1) * HALF_G, lane);

        if (comp) {
            const float4* lb = xb4 + half * HALF_G + c * 8;
            float4* pw = po + win * (W / 4);

            float4 A0, A1, A2, A3, A4, A5, A6, A7;
            float4 B0, B1, B2, B3, B4, B5, B6, B7;
            float4 C0, C1, C2, C3, C4, C5, C6, C7;
            float4 D0, D1, D2, D3, D4, D5, D6, D7;

            LOADG(A, 0)
            LOADG(B, 1)
            #pragma unroll 1
            for (int k2 = 0; k2 < 3; ++k2) {     // groups 4k2 .. 4k2+3
                const int g = 4 * k2;
                LOADG(C, g + 2) COMPG(A, g)       // every load issued 2
                LOADG(D, g + 3) COMPG(B, g + 1)   // groups (64 steps)
                LOADG(A, g + 4) COMPG(C, g + 2)   // before its consume
                LOADG(B, g + 5) COMPG(D, g + 3)
            }
            LOADG(C, 14) COMPG(A, 12)
            LOADG(D, 15) COMPG(B, 13)
            COMPG(C, 14)
            COMPG(D, 15)
        }
    }
}

__global__ void __launch_bounds__(64, 1)
dm_encode_kernel(const float* __restrict__ x,
                 const float* __restrict__ thp,
                 float* __restrict__ out,
                 const int nseq) {
    __shared__ float4 xb4[2 * HALF_G];            // 32 KiB, double-buffered

    const int lane     = threadIdx.x;
    const int seq_base = blockIdx.x * K;

    const float th  = fminf(fmaxf(thp[0], 0.01f), 0.5f);
    const float inv = 1.0f / th;                  // IEEE div, once
    const bool fast = (th * inv == 1.0f);         // wave-uniform

    if (fast) run<true >(xb4, x, out, th, inv, seq_base, nseq, lane);
    else      run<false>(xb4, x, out, th, inv, seq_base, nseq, lane);
}

extern "C" void kernel_launch(void* const* d_in, const int* in_sizes, int n_in,
                              void* d_out, int out_size, void* d_ws, size_t ws_size,
                              hipStream_t stream) {
    const float* x   = (const float*)d_in[0];
    const float* thp = (const float*)d_in[1];
    float* out       = (float*)d_out;

    const int nseq = in_sizes[0] / T_LEN;           // B*C = 2048
    const int grid = (nseq + K - 1) / K;            // 256 blocks, 1 wave each

    dm_encode_kernel<<<grid, 64, 0, stream>>>(x, thp, out, nseq);
}